// Round 15
// baseline (204.495 us; speedup 1.0000x reference)
//
#include <hip/hip_runtime.h>
#include <stdint.h>

// ---------------- problem constants ----------------
#define T_STEPS 2048
#define BATCH   32
#define NIN     512
#define NOUT    256
#define MROWS   (T_STEPS*BATCH)   // 65536
#define BO      (BATCH*NOUT)      // 8192
#define NCHUNK  32
#define CHLEN   (T_STEPS/NCHUNK)  // 64

typedef _Float16 f16x8 __attribute__((ext_vector_type(8)));
typedef _Float16 f16x4 __attribute__((ext_vector_type(4)));
typedef float    fx4   __attribute__((ext_vector_type(4)));

#define LDSP(p) ((__attribute__((address_space(3))) void*)(p))
#define GLBP(p) ((const __attribute__((address_space(1))) void*)(p))

#define BAR()        asm volatile("s_barrier" ::: "memory")
#define WAITLGKM0()  do { asm volatile("s_waitcnt lgkmcnt(0)" ::: "memory"); __builtin_amdgcn_sched_barrier(0); } while(0)
#define WAITVM(n)    do { asm volatile("s_waitcnt vmcnt(" #n ")" ::: "memory"); __builtin_amdgcn_sched_barrier(0); } while(0)

// ---------------- weights: 4x [256,512] f32 -> Wcat [1024][512] f16 -------
__global__ __launch_bounds__(256) void convert_w(
    const float* __restrict__ Wx, const float* __restrict__ Wf,
    const float* __restrict__ Wr, const float* __restrict__ Wc,
    _Float16* __restrict__ Wcat)
{
    int idx = blockIdx.x * 256 + threadIdx.x;
    int n  = idx >> 7;
    int k4 = (idx & 127) * 4;
    int g = n >> 8, o = n & 255;
    const float* W = (g == 0) ? Wx : (g == 1) ? Wf : (g == 2) ? Wr : Wc;
    float4 v = *(const float4*)(W + o * NIN + k4);
    f16x4 h;
    h[0] = (_Float16)v.x; h[1] = (_Float16)v.y;
    h[2] = (_Float16)v.z; h[3] = (_Float16)v.w;
    *(f16x4*)(Wcat + n * NIN + k4) = h;
}

// ---------------- 128x128 fused-A GEMM, 64 KiB LDS -> 2 blocks/CU ---------
// Rationale: at 256x128KiB the single resident block's barrier-synced waves
// ALTERNATE the LDS and MFMA pipes (util ~22%).  Two independent 4-wave
// blocks per CU overlap one block's staging with the other's MFMA.
// Per tile g (NGT=8): enter with A(g+1)x8 in flight;
//   STAGE_B(g+1) [4 vm, opposite parity] ; READ 16 frags ; lgkm0 ; 32 MFMA ;
//   WAITVM(0) [A(g+1) full-tile old, B(g+1) tile-minus-eps old] ;
//   AWRITE A(g+1) ; ALOAD A(g+2) ; lgkm0 ; BAR.
#define BM 128
#define BN 128
#define BK 64
#define NGT 8             // K / BK

__global__ __launch_bounds__(256, 2) void gemm_proj(
    const float*    __restrict__ xt,      // [MROWS][512] f32
    const _Float16* __restrict__ Wcat,    // [1024][512]  f16
    const float* __restrict__ bfv, const float* __restrict__ brv, const float* __restrict__ bcv,
    _Float16* __restrict__ xp_h, _Float16* __restrict__ f_h,
    _Float16* __restrict__ r_h,  _Float16* __restrict__ cx_h)
{
    __shared__ char lds[65536];  // A: [parity][128 rows][128B] ; B at +32768

    const int tid  = threadIdx.x;
    const int lane = tid & 63;
    const int w    = tid >> 6;       // 0..3
    const int wrq  = w >> 1;         // 0..1
    const int wcq  = w & 1;          // 0..1
    const int lr = lane & 15, lk = lane >> 4;

    // bijective XCD swizzle: 4096 wgs, 512/XCD; consecutive wg in an XCD
    // share a rowblk (A panel read by 8 cg-blocks -> 7/8 L2 hits).
    int wg = (blockIdx.x & 7) * 512 + (blockIdx.x >> 3);
    const int  rowblk = wg >> 3;     // 0..511
    const int  cg     = wg & 7;      // 0..7
    const long m0 = (long)rowblk * BM;
    const int  n0 = cg * BN;

    // ---- A staging maps (reg-staged f32, coalesced 16B/lane) ----
    // thread covers rows (tid>>4)+j*16, j=0..7; k-slot (tid&15):
    // 16B f32 global -> 8B f16 LDS (granule-consistent with 16B read swz).
    const char* baseAg = (const char*)xt + (m0 + (tid >> 4)) * 2048 + (tid & 15) * 16;
    const int awbase = (tid >> 4) * 128 + (((tid & 15) * 8) ^ (((tid >> 4) & 7) << 4));

    const int rl8  = lane >> 3;
    const int scol = (((lane & 7) ^ rl8) << 4);
    const char* baseB = (const char*)Wcat + ((long)(n0 + w * 8 + rl8)) * 1024 + scol;

    // single A reg set (static indexing only — rule 20)
    float4 av[8];
#define ALOAD(gi) do {                                                       \
        const char* _b = baseAg + ((gi) & 7) * 256;                          \
        _Pragma("unroll")                                                    \
        for (int jj = 0; jj < 8; ++jj)                                       \
            av[jj] = *(const float4*)(_b + jj * 32768);                      \
    } while (0)
#define AWRITE(gi) do {                                                      \
        char* _d = lds + ((gi) & 1) * 16384 + awbase;                        \
        _Pragma("unroll")                                                    \
        for (int jj = 0; jj < 8; ++jj) {                                     \
            f16x4 _h;                                                        \
            _h[0] = (_Float16)av[jj].x; _h[1] = (_Float16)av[jj].y;          \
            _h[2] = (_Float16)av[jj].z; _h[3] = (_Float16)av[jj].w;          \
            *(f16x4*)(_d + jj * 2048) = _h;                                  \
        }                                                                    \
    } while (0)
    // B tile 128x64 f16 = 16 KB: rows w*8+rl8 (+32 for 2nd instr) per half
#define STAGE_B(g, h) do {                                                   \
        char* _d = lds + 32768 + ((g) & 1) * 16384 + (h) * 8192 + w * 1024;  \
        const char* _s = baseB + ((g) & 7) * 128 + (long)(h) * 65536;        \
        __builtin_amdgcn_global_load_lds(GLBP(_s),         LDSP(_d),        16, 0, 0); \
        __builtin_amdgcn_global_load_lds(GLBP(_s + 32768), LDSP(_d + 4096), 16, 0, 0); \
    } while (0)

    fx4 acc[4][4];
    #pragma unroll
    for (int i = 0; i < 4; ++i)
        #pragma unroll
        for (int j = 0; j < 4; ++j) acc[i][j] = (fx4){0.f, 0.f, 0.f, 0.f};

    f16x8 Ar[4][2];    // A fragments [mf][kk]
    f16x8 Br[4][2];    // B fragments [nf][kk]

#define READ_A(c2) do {                                                      \
        _Pragma("unroll")                                                    \
        for (int mf = 0; mf < 4; ++mf) {                                     \
            int rl = wrq * 64 + mf * 16 + lr;                                \
            int rb = (c2) * 16384 + rl * 128;                                \
            _Pragma("unroll")                                                \
            for (int kk = 0; kk < 2; ++kk)                                   \
                Ar[mf][kk] = *(const f16x8*)(lds + rb +                      \
                    ((kk * 64 + lk * 16) ^ ((rl & 7) << 4)));                \
        }                                                                    \
    } while (0)
#define READ_B(c2) do {                                                      \
        _Pragma("unroll")                                                    \
        for (int nf = 0; nf < 4; ++nf) {                                     \
            int rl = wcq * 64 + nf * 16 + lr;                                \
            int rb = 32768 + (c2) * 16384 + rl * 128;                        \
            _Pragma("unroll")                                                \
            for (int kk = 0; kk < 2; ++kk)                                   \
                Br[nf][kk] = *(const f16x8*)(lds + rb +                      \
                    ((kk * 64 + lk * 16) ^ ((rl & 7) << 4)));                \
        }                                                                    \
    } while (0)
    // swapped operands: D[col=lane&15 -> m (A)], [reg j -> o (B)]
#define MMACC_ALL() do {                                                     \
        __builtin_amdgcn_s_setprio(1);                                       \
        _Pragma("unroll")                                                    \
        for (int kk = 0; kk < 2; ++kk)                                       \
            _Pragma("unroll")                                                \
            for (int mf = 0; mf < 4; ++mf)                                   \
                _Pragma("unroll")                                            \
                for (int nf = 0; nf < 4; ++nf)                               \
                    acc[mf][nf] = __builtin_amdgcn_mfma_f32_16x16x32_f16(    \
                        Br[nf][kk], Ar[mf][kk], acc[mf][nf], 0, 0, 0);       \
        __builtin_amdgcn_s_setprio(0);                                       \
    } while (0)

    const int g_out = cg >> 1;
    const int obase = (cg & 1) * 128;
    _Float16* outp = (g_out == 0) ? xp_h : (g_out == 1) ? f_h : (g_out == 2) ? r_h : cx_h;
    const float* bias = (g_out == 1) ? bfv : (g_out == 2) ? brv : (g_out == 3) ? bcv : nullptr;

    // ---- prologue: A(0)->LDS; B(0)->LDS; A(1) left in flight ----
    ALOAD(0);                                      // 8 vm
    STAGE_B(0, 0); STAGE_B(0, 1);                  // +4 = 12
    WAITVM(4);                                     // A(0) landed
    AWRITE(0);
    ALOAD(1);                                      // +8 = 12
    WAITVM(8);                                     // B(0) landed; leaves A(1)x8
    WAITLGKM0();                                   // A writes visible
    BAR();

    for (int g = 0; g < NGT; ++g) {
        const int c2 = g & 1;
        if (g + 1 < NGT) { STAGE_B(g + 1, 0); STAGE_B(g + 1, 1); }  // opp parity
        READ_A(c2);
        READ_B(c2);
        WAITLGKM0();
        MMACC_ALL();
        WAITVM(0);                       // A(g+1) full-tile old; B(g+1) L2-hot
        if (g + 1 < NGT) {
            AWRITE(g + 1);               // reg set now dead ->
            if (g + 2 < NGT) ALOAD(g + 2);   // reload immediately
        }
        WAITLGKM0();                     // A ds_writes + frag reads complete
        BAR();                           // single tile-boundary barrier
    }

    // ---- epilogue: packed f16x4 stores ----
    #pragma unroll
    for (int nf = 0; nf < 4; ++nf) {
        const int ob = obase + wcq * 64 + nf * 16 + lk * 4;
        float4 bv4 = (g_out == 0) ? (float4){0.f, 0.f, 0.f, 0.f}
                                  : *(const float4*)(bias + ob);
        #pragma unroll
        for (int mf = 0; mf < 4; ++mf) {
            long row = m0 + wrq * 64 + mf * 16 + lr;
            fx4 v = acc[mf][nf];
            f16x4 hv;
            if (g_out == 1 || g_out == 2) {
                float p0 = v[0] + bv4.x, p1 = v[1] + bv4.y;
                float p2 = v[2] + bv4.z, p3 = v[3] + bv4.w;
                hv[0] = (_Float16)(__builtin_amdgcn_rcpf(1.0f + __expf(-p0)));
                hv[1] = (_Float16)(__builtin_amdgcn_rcpf(1.0f + __expf(-p1)));
                hv[2] = (_Float16)(__builtin_amdgcn_rcpf(1.0f + __expf(-p2)));
                hv[3] = (_Float16)(__builtin_amdgcn_rcpf(1.0f + __expf(-p3)));
            } else {
                hv[0] = (_Float16)(v[0] + bv4.x);
                hv[1] = (_Float16)(v[1] + bv4.y);
                hv[2] = (_Float16)(v[2] + bv4.z);
                hv[3] = (_Float16)(v[3] + bv4.w);
            }
            *(f16x4*)(outp + row * NOUT + ob) = hv;
        }
    }
}

// ---------------- pass 2a: per-chunk affine composition (f16x4 loads) -----
__global__ __launch_bounds__(256) void chunk_scan_a(
    const _Float16* __restrict__ f_h, const _Float16* __restrict__ xp_h,
    float* __restrict__ chunkA, float* __restrict__ chunkB)
{
    int tid2 = blockIdx.x * 256 + threadIdx.x;   // 65536 threads
    int ch = tid2 >> 11;
    int b4 = (tid2 & 2047) << 2;                 // 4 consecutive bo lanes
    long base = (long)ch * CHLEN * BO + b4;
    fx4 a = (fx4){1.f, 1.f, 1.f, 1.f};
    fx4 cc = (fx4){0.f, 0.f, 0.f, 0.f};
    for (int s = 0; s < CHLEN; ++s) {
        long i = base + (long)s * BO;
        f16x4 fv = *(const f16x4*)(f_h + i);
        f16x4 xv = *(const f16x4*)(xp_h + i);
        #pragma unroll
        for (int q = 0; q < 4; ++q) {
            float f = (float)fv[q], x = (float)xv[q];
            cc[q] = f * cc[q] + (1.f - f) * x;
            a[q] *= f;
        }
    }
    *(fx4*)(chunkA + ch * BO + b4) = a;
    *(fx4*)(chunkB + ch * BO + b4) = cc;
}

// ---------------- pass 2b: propagate chunk states ----
__global__ __launch_bounds__(256) void chunk_prop(
    const float* __restrict__ ct0,
    const float* __restrict__ chunkA, const float* __restrict__ chunkB,
    float* __restrict__ cin, float* __restrict__ c_final)
{
    int bo = blockIdx.x * 256 + threadIdx.x;   // 8192
    float c = ct0[bo];
    #pragma unroll
    for (int ch = 0; ch < NCHUNK; ++ch) {
        cin[ch * BO + bo] = c;
        c = chunkA[ch * BO + bo] * c + chunkB[ch * BO + bo];
    }
    c_final[bo] = c;
}

// ---------------- pass 2c: final scan producing ht (f16x4/float4) --------
__global__ __launch_bounds__(256) void chunk_scan_h(
    const _Float16* __restrict__ xp_h, const _Float16* __restrict__ f_h,
    const _Float16* __restrict__ r_h,  const _Float16* __restrict__ cx_h,
    const float* __restrict__ cin, float* __restrict__ ht)
{
    int tid2 = blockIdx.x * 256 + threadIdx.x;   // 65536 threads
    int ch = tid2 >> 11;
    int b4 = (tid2 & 2047) << 2;
    long base = (long)ch * CHLEN * BO + b4;
    fx4 c = *(const fx4*)(cin + ch * BO + b4);
    for (int s = 0; s < CHLEN; ++s) {
        long i = base + (long)s * BO;
        f16x4 fv  = *(const f16x4*)(f_h + i);
        f16x4 xv  = *(const f16x4*)(xp_h + i);
        f16x4 rv  = *(const f16x4*)(r_h + i);
        f16x4 cxv = *(const f16x4*)(cx_h + i);
        fx4 h4;
        #pragma unroll
        for (int q = 0; q < 4; ++q) {
            float f = (float)fv[q], x = (float)xv[q];
            float r = (float)rv[q], cx = (float)cxv[q];
            c[q] = f * c[q] + (1.f - f) * x;
            float e = __expf(2.f * c[q]);                  // tanh=(e-1)/(e+1)
            float th = (e - 1.f) * __builtin_amdgcn_rcpf(e + 1.f);
            h4[q] = r * th + (1.f - r) * cx;
        }
        *(fx4*)(ht + i) = h4;
    }
}

// ---------------- launcher ----------------
extern "C" void kernel_launch(void* const* d_in, const int* in_sizes, int n_in,
                              void* d_out, int out_size, void* d_ws, size_t ws_size,
                              hipStream_t stream) {
    const float* xt  = (const float*)d_in[0];
    const float* ct0 = (const float*)d_in[1];
    const float* Wx  = (const float*)d_in[2];
    const float* Wf  = (const float*)d_in[3];
    const float* bf_ = (const float*)d_in[4];
    const float* Wr  = (const float*)d_in[5];
    const float* br_ = (const float*)d_in[6];
    const float* Wc  = (const float*)d_in[7];
    const float* bc_ = (const float*)d_in[8];

    float* ht      = (float*)d_out;
    float* c_final = ht + (size_t)MROWS * NOUT;

    char* ws = (char*)d_ws;
    _Float16* Wcat = (_Float16*)ws;                          // 1 MiB
    _Float16* xp_h = (_Float16*)(ws + (1 << 20));            // 32 MiB each
    _Float16* f_h  = xp_h + (size_t)MROWS * NOUT;
    _Float16* r_h  = f_h  + (size_t)MROWS * NOUT;
    _Float16* cx_h = r_h  + (size_t)MROWS * NOUT;
    float* chunkA  = (float*)(cx_h + (size_t)MROWS * NOUT);  // 1 MiB
    float* chunkB  = chunkA + NCHUNK * BO;
    float* cin     = chunkB + NCHUNK * BO;
    // total ws use ~ 132 MiB

    convert_w<<<512, 256, 0, stream>>>(Wx, Wf, Wr, Wc, Wcat);
    gemm_proj<<<(MROWS / BM) * 8, 256, 0, stream>>>(
        xt, Wcat, bf_, br_, bc_, xp_h, f_h, r_h, cx_h);
    chunk_scan_a<<<256, 256, 0, stream>>>(f_h, xp_h, chunkA, chunkB);
    chunk_prop<<<BO / 256, 256, 0, stream>>>(ct0, chunkA, chunkB, cin, c_final);
    chunk_scan_h<<<256, 256, 0, stream>>>(xp_h, f_h, r_h, cx_h, cin, ht);
}